// Round 12
// baseline (497.216 us; speedup 1.0000x reference)
//
#include <hip/hip_runtime.h>
#include <hip/hip_bf16.h>

#define KK 50      // triples per (b,t)
#define DD 100
#define TWO_D 200
#define DPAD 112   // padded output-feature dim (7 * 16)
#define KHT 224    // packed K for head_tail gemm: [head 100+pad12 | tail 100+pad12]
#define KRL 128    // padded K for relation gemm (4 * 32)

#define NROWS 150  // 50 triples * {head, rel, tail}
#define TP 104     // LDS row pitch (bf16 elems) = 208 B
// LDS map (bytes): [0,31232) rows+overread pad; [31232,32512) = sIds (gather phase)
// ALIASED with sEp[4][64]+sAl[64] (post-GEMM phase). Max GEMM over-read = 31216.
#define SX_DATA 31232
#define SEP_OFF 31232
#define SAL_OFF 32256
#define SX_TOTAL 32512          // rounds to 32768 -> 5 blocks/CU
#define NCH_RAW (NROWS * 25)    // 3750 4-elem chunks per block

// workspace layout (bytes)
#define WS_FLAGS 0                        // [0]=f32 [1]=ids64
#define WS_WHT 256                        // bf16[DPAD*KHT]  = 50176 B
#define WS_WRL (WS_WHT + DPAD*KHT*2)      // bf16[DPAD*KRL]  = 28672 B
#define WS_BHT (WS_WRL + DPAD*KRL*2)      // bf16[DPAD] (256 B slot)
#define WS_BRL (WS_BHT + 256)

typedef __attribute__((ext_vector_type(8))) short        s8v;
typedef __attribute__((ext_vector_type(8))) __bf16       b8v;
typedef __attribute__((ext_vector_type(4))) __bf16       b4v;
typedef __attribute__((ext_vector_type(4))) float        f32x4;

// --- MFMA shim: tolerate either builtin signature (short8 or bf16x8 operands) ---
template <typename T>
__device__ __forceinline__ auto mfma_try(T a, T b, f32x4 c, int)
    -> decltype(__builtin_amdgcn_mfma_f32_16x16x32_bf16(a, b, c, 0, 0, 0)) {
    return __builtin_amdgcn_mfma_f32_16x16x32_bf16(a, b, c, 0, 0, 0);
}
template <typename T, typename U = b8v>
__device__ __forceinline__ f32x4 mfma_try(T a, T b, f32x4 c, long) {
    U ab = __builtin_bit_cast(U, a);
    U bb = __builtin_bit_cast(U, b);
    return __builtin_amdgcn_mfma_f32_16x16x32_bf16(ab, bb, c, 0, 0, 0);
}
__device__ __forceinline__ f32x4 mfma16x16x32_bf16(s8v a, s8v b, f32x4 c) {
    return mfma_try(a, b, c, 0);
}

__device__ __forceinline__ float bf2f(__hip_bfloat16 h) { return __bfloat162float(h); }

__device__ __forceinline__ float tanh_fast(float x) {
    float e = __expf(2.f * x);
    return 1.f - 2.f * __builtin_amdgcn_rcpf(e + 1.f);
}

// ---------- weight prep with SELF-DETECTION (detect_dtypes merged in) ----------
// Wave 0 of every block detects dtypes (emb exponent probe + ids odd-word probe);
// block 0 publishes flags to ws for the fused kernel.
__global__ void prep_weights(const void* __restrict__ Wht, const void* __restrict__ bht,
                             const void* __restrict__ Wrl, const void* __restrict__ brl,
                             const unsigned int* __restrict__ emb_raw,
                             const unsigned int* __restrict__ ids_raw,
                             void* __restrict__ ws) {
    __shared__ int sFlags[2];
    const int tid = threadIdx.x;
    if (tid < 64) {
        int f32d = 0;
        #pragma unroll
        for (int rep = 0; rep < 4; rep++) {
            unsigned int wd = emb_raw[tid + rep * 64];
            unsigned int e0 = (wd >> 7)  & 0xFF;
            unsigned int e1 = (wd >> 23) & 0xFF;
            if (e0 >= 0x87 || e1 >= 0x87) f32d = 1;   // |x|>=256 impossible
        }
        unsigned long long mf = __ballot(f32d != 0);
        unsigned long long mz = __ballot(ids_raw[2 * tid + 1] == 0u);
        if (tid == 0) {
            sFlags[0] = mf ? 1 : 0;
            sFlags[1] = (__popcll(mz) >= 32) ? 1 : 0;
        }
    }
    __syncthreads();
    const bool f32 = sFlags[0] != 0;
    if (blockIdx.x == 0 && tid == 0) {
        ((int*)ws)[0] = sFlags[0];
        ((int*)ws)[1] = sFlags[1];
    }

    __hip_bfloat16* whtp = (__hip_bfloat16*)((char*)ws + WS_WHT);
    __hip_bfloat16* wrlp = (__hip_bfloat16*)((char*)ws + WS_WRL);
    __hip_bfloat16* bhtp = (__hip_bfloat16*)((char*)ws + WS_BHT);
    __hip_bfloat16* brlp = (__hip_bfloat16*)((char*)ws + WS_BRL);

    const int gid = blockIdx.x * blockDim.x + tid;
    const int gs  = gridDim.x * blockDim.x;

    // ht feature axis packed: k<112 -> head k (k<100 else 0); k>=112 -> tail k-112.
    for (int i = gid; i < DPAD * KHT; i += gs) {
        int d = i / KHT, f = i - d * KHT;
        int src = -1;
        if (f < 112) { if (f < DD) src = f; }
        else { int t = f - 112; if (t < DD) src = DD + t; }
        float v = 0.f;
        if (d < DD && src >= 0)
            v = f32 ? ((const float*)Wht)[d * TWO_D + src]
                    : bf2f(((const __hip_bfloat16*)Wht)[d * TWO_D + src]);
        whtp[i] = __float2bfloat16(v);
    }
    for (int i = gid; i < DPAD * KRL; i += gs) {
        int d = i / KRL, f = i - d * KRL;
        float v = 0.f;
        if (d < DD && f < DD)
            v = f32 ? ((const float*)Wrl)[d * DD + f]
                    : bf2f(((const __hip_bfloat16*)Wrl)[d * DD + f]);
        wrlp[i] = __float2bfloat16(v);
    }
    for (int i = gid; i < DPAD; i += gs) {
        float vh = 0.f, vr = 0.f;
        if (i < DD) {
            vh = f32 ? ((const float*)bht)[i] : bf2f(((const __hip_bfloat16*)bht)[i]);
            vr = f32 ? ((const float*)brl)[i] : bf2f(((const __hip_bfloat16*)brl)[i]);
        }
        bhtp[i] = __float2bfloat16(vh);
        brlp[i] = __float2bfloat16(vr);
    }
}

// ---------- gathers into LINEAR LDS: row seg at byte seg*208 (pitch 104 elems) ------
template <int CNT>
__device__ __forceinline__ void gather_f32(const float* __restrict__ embf,
                                           const int* __restrict__ sIds,
                                           char* __restrict__ sX, int tid, int base) {
    float4 v[CNT];
    int doff[CNT];
    #pragma unroll
    for (int i = 0; i < CNT; ++i) {
        int c = tid + (base + i) * 256;
        bool ok = (c < NCH_RAW);
        int cc = ok ? c : 0;
        int seg = cc / 25;
        int off = (cc - seg * 25) * 4;
        size_t id = (size_t)sIds[seg];
        v[i] = *(const float4*)(embf + id * DD + off);   // 16B aligned (row = 400B)
        doff[i] = ok ? (seg * (TP * 2) + off * 2) : -1;
    }
    #pragma unroll
    for (int i = 0; i < CNT; ++i) {
        if (doff[i] >= 0) {
            b4v pk = { (__bf16)v[i].x, (__bf16)v[i].y, (__bf16)v[i].z, (__bf16)v[i].w };
            *(b4v*)(sX + doff[i]) = pk;                  // 8B aligned
        }
    }
}

template <int CNT>
__device__ __forceinline__ void gather_b16raw(const __hip_bfloat16* __restrict__ embh,
                                              const int* __restrict__ sIds,
                                              char* __restrict__ sX, int tid, int base) {
    uint2 v[CNT];
    int doff[CNT];
    #pragma unroll
    for (int i = 0; i < CNT; ++i) {
        int c = tid + (base + i) * 256;
        bool ok = (c < NCH_RAW);
        int cc = ok ? c : 0;
        int seg = cc / 25;
        int off = (cc - seg * 25) * 4;
        size_t id = (size_t)sIds[seg];
        v[i] = *(const uint2*)(embh + id * DD + off);    // 8B aligned (row = 200B)
        doff[i] = ok ? (seg * (TP * 2) + off * 2) : -1;
    }
    #pragma unroll
    for (int i = 0; i < CNT; ++i) {
        if (doff[i] >= 0) *(uint2*)(sX + doff[i]) = v[i];
    }
}

// m-batched (pairs), d-split GEMM:
//   wave w owns d-tiles {nt0,nt1}; two serial m-pair passes (m={0,1} then {2,3})
//   keep peak accumulators at ~48 regs so (256,5) fits WITHOUT spill.
//   B-fragment reuse: 2x per load within a pass (4x total across block).
__global__ __launch_bounds__(256, 5) void fused_outer_encoder(
    const int* __restrict__ ids,              // int32 or int64 (flagged)
    const void* __restrict__ emb_raw,         // fp32 or bf16 (flagged), [V][DD]
    const void* __restrict__ ws,
    float* __restrict__ out)                  // [NBT][TWO_D] fp32
{
    __shared__ char sX[SX_TOTAL];
    int*   sIds = (int*)(sX + SEP_OFF);       // gather-phase use of tail region
    float* sEp  = (float*)(sX + SEP_OFF);     // post-GEMM alias (sIds dead by then)
    float* sAl  = (float*)(sX + SAL_OFF);

    const int* flags = (const int*)ws;
    const __hip_bfloat16* whtp = (const __hip_bfloat16*)((const char*)ws + WS_WHT);
    const __hip_bfloat16* wrlp = (const __hip_bfloat16*)((const char*)ws + WS_WRL);
    const __hip_bfloat16* bhtp = (const __hip_bfloat16*)((const char*)ws + WS_BHT);
    const __hip_bfloat16* brlp = (const __hip_bfloat16*)((const char*)ws + WS_BRL);

    const int tid = threadIdx.x;
    const int bt  = blockIdx.x;
    const bool f32      = flags[0] != 0;
    const int idsStride = flags[1] ? 2 : 1;   // int64: read low word

    // ---- issue ids load first ----
    int myid = 0;
    if (tid < NROWS) myid = ids[(bt * NROWS + tid) * idsStride];

    // ---- zero row pads (elems 100-103 of each row) + bytes [31200,31232)
    //      (branchless over-read targets; NaN-bit safety; max over-read = 31216) ----
    for (int i = tid; i < 154; i += 256) {
        int byteoff = (i < 150) ? (i * (TP * 2) + 200) : (31200 + (i - 150) * 8);
        *(uint2*)(sX + byteoff) = make_uint2(0u, 0u);
    }
    if (tid < NROWS) sIds[tid] = myid;
    __syncthreads();

    // ---- gather 150 rows -> LDS bf16 (on-the-fly cvt for fp32) ----
    if (f32) {
        const float* embf = (const float*)emb_raw;
        gather_f32<8>(embf, sIds, sX, tid, 0);
        gather_f32<7>(embf, sIds, sX, tid, 8);
    } else {
        const __hip_bfloat16* embh = (const __hip_bfloat16*)emb_raw;
        gather_b16raw<8>(embh, sIds, sX, tid, 0);
        gather_b16raw<7>(embh, sIds, sX, tid, 8);
    }
    __syncthreads();
    // NOTE: after this barrier sIds is dead; sEp/sAl may overwrite it. GEMM reads
    // stay < SX_DATA, so concurrent sEp writes by finished waves are never read
    // by GEMM (its over-reads cap at 31216 < 31232).

    const int lane = tid & 63;
    const int w    = tid >> 6;
    const int n    = lane & 15;       // B col (feature) / A row-within-tile selector
    const int q    = lane >> 4;       // quad: k-slice q*8 within each 32-k window
    const int nt0  = (w < 3) ? 2 * w : 6;
    const int nt1  = (w < 3) ? 2 * w + 1 : 6;     // wave3 dup of tile 6, masked
    const float m1 = (w < 3) ? 1.f : 0.f;

    const __hip_bfloat16* sxe = (const __hip_bfloat16*)sX;
    const float bh0 = bf2f(bhtp[nt0 * 16 + n]);
    const float bh1 = bf2f(bhtp[nt1 * 16 + n]);
    const float br0 = bf2f(brlp[nt0 * 16 + n]);
    const float br1 = bf2f(brlp[nt1 * 16 + n]);

    // ---- two serial m-pair passes (register-pressure cap for (256,5)) ----
    #pragma unroll 1
    for (int mp = 0; mp < 2; mp++) {
        int ar0 = mp * 32 + n;      if (ar0 >= KK) ar0 = KK - 1;
        int ar1 = mp * 32 + 16 + n; if (ar1 >= KK) ar1 = KK - 1;
        const int hb0 = 3 * ar0 * TP;
        const int hb1 = 3 * ar1 * TP;

        // head_tail GEMM: K=224 packed [head 112 | tail 112]
        f32x4 accH[2][2];
        #pragma unroll
        for (int mi = 0; mi < 2; mi++)
            #pragma unroll
            for (int t = 0; t < 2; t++)
                #pragma unroll
                for (int j = 0; j < 4; j++) accH[mi][t][j] = 0.f;

        #pragma unroll
        for (int ks = 0; ks < 7; ks++) {
            const int c    = ks * 4 + q;
            const int aoff = (c < 14) ? (c * 8) : (2 * TP + (c - 14) * 8);
            s8v b0 = *(const s8v*)(whtp + (nt0 * 16 + n) * KHT + ks * 32 + q * 8);
            s8v b1 = *(const s8v*)(whtp + (nt1 * 16 + n) * KHT + ks * 32 + q * 8);
            s8v a0 = *(const s8v*)(sxe + hb0 + aoff);
            s8v a1 = *(const s8v*)(sxe + hb1 + aoff);
            accH[0][0] = mfma16x16x32_bf16(a0, b0, accH[0][0]);
            accH[0][1] = mfma16x16x32_bf16(a0, b1, accH[0][1]);
            accH[1][0] = mfma16x16x32_bf16(a1, b0, accH[1][0]);
            accH[1][1] = mfma16x16x32_bf16(a1, b1, accH[1][1]);
        }

        float htv[2][2][4];
        #pragma unroll
        for (int mi = 0; mi < 2; mi++)
            #pragma unroll
            for (int j = 0; j < 4; j++) {
                htv[mi][0][j] = tanh_fast(accH[mi][0][j] + bh0);
                htv[mi][1][j] = tanh_fast(accH[mi][1][j] + bh1);
            }

        // relation GEMM: K=128; rel row at hb+TP; over-reads roll into tail x W0
        f32x4 accR[2][2];
        #pragma unroll
        for (int mi = 0; mi < 2; mi++)
            #pragma unroll
            for (int t = 0; t < 2; t++)
                #pragma unroll
                for (int j = 0; j < 4; j++) accR[mi][t][j] = 0.f;

        #pragma unroll
        for (int ks = 0; ks < 4; ks++) {
            const int c    = ks * 4 + q;
            const int aoff = TP + c * 8;
            s8v b0 = *(const s8v*)(wrlp + (nt0 * 16 + n) * KRL + ks * 32 + q * 8);
            s8v b1 = *(const s8v*)(wrlp + (nt1 * 16 + n) * KRL + ks * 32 + q * 8);
            s8v a0 = *(const s8v*)(sxe + hb0 + aoff);
            s8v a1 = *(const s8v*)(sxe + hb1 + aoff);
            accR[0][0] = mfma16x16x32_bf16(a0, b0, accR[0][0]);
            accR[0][1] = mfma16x16x32_bf16(a0, b1, accR[0][1]);
            accR[1][0] = mfma16x16x32_bf16(a1, b0, accR[1][0]);
            accR[1][1] = mfma16x16x32_bf16(a1, b1, accR[1][1]);
        }

        // combine (tile 1 masked for wave 3) + n-lane reduce + partial store
        float dj[2][4];
        #pragma unroll
        for (int mi = 0; mi < 2; mi++)
            #pragma unroll
            for (int j = 0; j < 4; j++)
                dj[mi][j] = (accR[mi][0][j] + br0) * htv[mi][0][j]
                          + m1 * (accR[mi][1][j] + br1) * htv[mi][1][j];

        #pragma unroll
        for (int mask = 1; mask < 16; mask <<= 1)
            #pragma unroll
            for (int mi = 0; mi < 2; mi++)
                #pragma unroll
                for (int j = 0; j < 4; j++)
                    dj[mi][j] += __shfl_xor(dj[mi][j], mask, 64);

        if (n == 0) {
            #pragma unroll
            for (int mi = 0; mi < 2; mi++)
                #pragma unroll
                for (int j = 0; j < 4; j++)
                    sEp[w * 64 + mp * 32 + mi * 16 + q * 4 + j] = dj[mi][j];
        }
    }
    __syncthreads();

    // ---- softmax over KK triples (wave 0 sums the 4 wave-partials) ----
    if (tid < 64) {
        float e = sEp[0 * 64 + tid] + sEp[1 * 64 + tid]
                + sEp[2 * 64 + tid] + sEp[3 * 64 + tid];
        float v = (tid < KK) ? e : -3.0e38f;
        float mx = v;
        #pragma unroll
        for (int mask = 1; mask < 64; mask <<= 1) mx = fmaxf(mx, __shfl_xor(mx, mask, 64));
        float p = (tid < KK) ? __expf(v - mx) : 0.f;
        float s = p;
        #pragma unroll
        for (int mask = 1; mask < 64; mask <<= 1) s += __shfl_xor(s, mask, 64);
        if (tid < KK) sAl[tid] = p / s;
    }
    __syncthreads();

    // ---- output: out[bt][d] = sum_k alpha[k] * head_tail[k][d] (LDS bf16 rows) ----
    if (tid < TWO_D) {
        const int half  = tid / DD;            // 0=head, 1=tail
        const int dmod  = tid - half * DD;
        const int roff  = half ? 2 : 0;
        float acc = 0.f;
        #pragma unroll 10
        for (int k = 0; k < KK; k++)
            acc += sAl[k] * bf2f(sxe[(3 * k + roff) * TP + dmod]);
        out[(size_t)bt * TWO_D + tid] = acc;
    }
}

extern "C" void kernel_launch(void* const* d_in, const int* in_sizes, int n_in,
                              void* d_out, int out_size, void* d_ws, size_t ws_size,
                              hipStream_t stream) {
    const int*  ids = (const int*)d_in[1];
    const void* emb = d_in[3];
    const void* Wht = d_in[4];
    const void* bht = d_in[5];
    const void* Wrl = d_in[6];
    const void* brl = d_in[7];
    float* out = (float*)d_out;

    const int nbt = in_sizes[1] / NROWS;   // B*T blocks

    hipLaunchKernelGGL(prep_weights, dim3(64), dim3(256), 0, stream,
                       Wht, bht, Wrl, brl,
                       (const unsigned int*)emb, (const unsigned int*)ids, d_ws);
    hipLaunchKernelGGL(fused_outer_encoder, dim3(nbt), dim3(256), 0, stream,
                       ids, emb, (const void*)d_ws, out);
}

// Round 13
// 371.390 us; speedup vs baseline: 1.3388x; 1.3388x over previous
//
#include <hip/hip_runtime.h>
#include <hip/hip_bf16.h>

#define KK 50      // triples per (b,t)
#define DD 100
#define TWO_D 200
#define DPAD 112   // padded output-feature dim (7 * 16)
#define KHT 224    // packed K for head_tail gemm: [head 100+pad12 | tail 100+pad12]
#define KRL 128    // padded K for relation gemm (4 * 32)

#define NROWS 150  // 50 triples * {head, rel, tail}
#define TP 104     // LDS row pitch (bf16 elems) = 208 B
// LDS map (bytes): [0,31232) rows + zeroed overread pad (max over-read = 31216+8);
// [31232,32512): sIds (gather phase) ALIASED with sEp[256]+sAl[64] (post-GEMM).
#define SX_DATA 31232
#define SEP_OFF 31232
#define SAL_OFF 32256
#define SX_TOTAL 32512          // rounds to 32768 -> 5 blocks/CU by LDS
#define NCH_RAW (NROWS * 25)    // 3750 4-elem chunks per block

// workspace layout (bytes)
#define WS_FLAGS 0                        // [0]=f32 [1]=ids64
#define WS_WHT 256                        // bf16[DPAD*KHT]  = 50176 B
#define WS_WRL (WS_WHT + DPAD*KHT*2)      // bf16[DPAD*KRL]  = 28672 B
#define WS_BHT (WS_WRL + DPAD*KRL*2)      // bf16[DPAD] (256 B slot)
#define WS_BRL (WS_BHT + 256)

typedef __attribute__((ext_vector_type(8))) short        s8v;
typedef __attribute__((ext_vector_type(8))) __bf16       b8v;
typedef __attribute__((ext_vector_type(4))) __bf16       b4v;
typedef __attribute__((ext_vector_type(4))) float        f32x4;

// --- MFMA shim: tolerate either builtin signature (short8 or bf16x8 operands) ---
template <typename T>
__device__ __forceinline__ auto mfma_try(T a, T b, f32x4 c, int)
    -> decltype(__builtin_amdgcn_mfma_f32_16x16x32_bf16(a, b, c, 0, 0, 0)) {
    return __builtin_amdgcn_mfma_f32_16x16x32_bf16(a, b, c, 0, 0, 0);
}
template <typename T, typename U = b8v>
__device__ __forceinline__ f32x4 mfma_try(T a, T b, f32x4 c, long) {
    U ab = __builtin_bit_cast(U, a);
    U bb = __builtin_bit_cast(U, b);
    return __builtin_amdgcn_mfma_f32_16x16x32_bf16(ab, bb, c, 0, 0, 0);
}
__device__ __forceinline__ f32x4 mfma16x16x32_bf16(s8v a, s8v b, f32x4 c) {
    return mfma_try(a, b, c, 0);
}

__device__ __forceinline__ float bf2f(__hip_bfloat16 h) { return __bfloat162float(h); }

__device__ __forceinline__ float tanh_fast(float x) {
    float e = __expf(2.f * x);
    return 1.f - 2.f * __builtin_amdgcn_rcpf(e + 1.f);
}

// ---------- weight prep with SELF-DETECTION (merged detect; verified r12) ----------
__global__ void prep_weights(const void* __restrict__ Wht, const void* __restrict__ bht,
                             const void* __restrict__ Wrl, const void* __restrict__ brl,
                             const unsigned int* __restrict__ emb_raw,
                             const unsigned int* __restrict__ ids_raw,
                             void* __restrict__ ws) {
    __shared__ int sFlags[2];
    const int tid = threadIdx.x;
    if (tid < 64) {
        int f32d = 0;
        #pragma unroll
        for (int rep = 0; rep < 4; rep++) {
            unsigned int wd = emb_raw[tid + rep * 64];
            unsigned int e0 = (wd >> 7)  & 0xFF;
            unsigned int e1 = (wd >> 23) & 0xFF;
            if (e0 >= 0x87 || e1 >= 0x87) f32d = 1;   // |x|>=256 impossible
        }
        unsigned long long mf = __ballot(f32d != 0);
        unsigned long long mz = __ballot(ids_raw[2 * tid + 1] == 0u);
        if (tid == 0) {
            sFlags[0] = mf ? 1 : 0;
            sFlags[1] = (__popcll(mz) >= 32) ? 1 : 0;
        }
    }
    __syncthreads();
    const bool f32 = sFlags[0] != 0;
    if (blockIdx.x == 0 && tid == 0) {
        ((int*)ws)[0] = sFlags[0];
        ((int*)ws)[1] = sFlags[1];
    }

    __hip_bfloat16* whtp = (__hip_bfloat16*)((char*)ws + WS_WHT);
    __hip_bfloat16* wrlp = (__hip_bfloat16*)((char*)ws + WS_WRL);
    __hip_bfloat16* bhtp = (__hip_bfloat16*)((char*)ws + WS_BHT);
    __hip_bfloat16* brlp = (__hip_bfloat16*)((char*)ws + WS_BRL);

    const int gid = blockIdx.x * blockDim.x + tid;
    const int gs  = gridDim.x * blockDim.x;

    // ht feature axis packed: k<112 -> head k (k<100 else 0); k>=112 -> tail k-112.
    for (int i = gid; i < DPAD * KHT; i += gs) {
        int d = i / KHT, f = i - d * KHT;
        int src = -1;
        if (f < 112) { if (f < DD) src = f; }
        else { int t = f - 112; if (t < DD) src = DD + t; }
        float v = 0.f;
        if (d < DD && src >= 0)
            v = f32 ? ((const float*)Wht)[d * TWO_D + src]
                    : bf2f(((const __hip_bfloat16*)Wht)[d * TWO_D + src]);
        whtp[i] = __float2bfloat16(v);
    }
    for (int i = gid; i < DPAD * KRL; i += gs) {
        int d = i / KRL, f = i - d * KRL;
        float v = 0.f;
        if (d < DD && f < DD)
            v = f32 ? ((const float*)Wrl)[d * DD + f]
                    : bf2f(((const __hip_bfloat16*)Wrl)[d * DD + f]);
        wrlp[i] = __float2bfloat16(v);
    }
    for (int i = gid; i < DPAD; i += gs) {
        float vh = 0.f, vr = 0.f;
        if (i < DD) {
            vh = f32 ? ((const float*)bht)[i] : bf2f(((const __hip_bfloat16*)bht)[i]);
            vr = f32 ? ((const float*)brl)[i] : bf2f(((const __hip_bfloat16*)brl)[i]);
        }
        bhtp[i] = __float2bfloat16(vh);
        brlp[i] = __float2bfloat16(vr);
    }
}

// ---------- gathers into LINEAR LDS: row seg at byte seg*208 (pitch 104 elems) ------
template <int CNT>
__device__ __forceinline__ void gather_f32(const float* __restrict__ embf,
                                           const int* __restrict__ sIds,
                                           char* __restrict__ sX, int tid, int base) {
    float4 v[CNT];
    int doff[CNT];
    #pragma unroll
    for (int i = 0; i < CNT; ++i) {
        int c = tid + (base + i) * 256;
        bool ok = (c < NCH_RAW);
        int cc = ok ? c : 0;
        int seg = cc / 25;
        int off = (cc - seg * 25) * 4;
        size_t id = (size_t)sIds[seg];
        v[i] = *(const float4*)(embf + id * DD + off);   // 16B aligned (row = 400B)
        doff[i] = ok ? (seg * (TP * 2) + off * 2) : -1;
    }
    #pragma unroll
    for (int i = 0; i < CNT; ++i) {
        if (doff[i] >= 0) {
            b4v pk = { (__bf16)v[i].x, (__bf16)v[i].y, (__bf16)v[i].z, (__bf16)v[i].w };
            *(b4v*)(sX + doff[i]) = pk;                  // 8B aligned
        }
    }
}

template <int CNT>
__device__ __forceinline__ void gather_b16raw(const __hip_bfloat16* __restrict__ embh,
                                              const int* __restrict__ sIds,
                                              char* __restrict__ sX, int tid, int base) {
    uint2 v[CNT];
    int doff[CNT];
    #pragma unroll
    for (int i = 0; i < CNT; ++i) {
        int c = tid + (base + i) * 256;
        bool ok = (c < NCH_RAW);
        int cc = ok ? c : 0;
        int seg = cc / 25;
        int off = (cc - seg * 25) * 4;
        size_t id = (size_t)sIds[seg];
        v[i] = *(const uint2*)(embh + id * DD + off);    // 8B aligned (row = 200B)
        doff[i] = ok ? (seg * (TP * 2) + off * 2) : -1;
    }
    #pragma unroll
    for (int i = 0; i < CNT; ++i) {
        if (doff[i] >= 0) *(uint2*)(sX + doff[i]) = v[i];
    }
}

// m-batched, d-split GEMM (r11 structure, UNCHANGED — 147 us, no spill):
//   wave w owns d-tiles {2w, 2w+1} (w<3) or {6, dup-masked} (w=3), computed for
//   ALL 4 m-tiles; B fragments reused 4x per load.
__global__ __launch_bounds__(256, 4) void fused_outer_encoder(
    const int* __restrict__ ids,              // int32 or int64 (flagged)
    const void* __restrict__ emb_raw,         // fp32 or bf16 (flagged), [V][DD]
    const void* __restrict__ ws,
    float* __restrict__ out)                  // [NBT][TWO_D] fp32
{
    __shared__ char sX[SX_TOTAL];
    int*   sIds = (int*)(sX + SEP_OFF);       // gather-phase use of tail region
    float* sEp  = (float*)(sX + SEP_OFF);     // post-GEMM alias (sIds dead by then)
    float* sAl  = (float*)(sX + SAL_OFF);

    const int* flags = (const int*)ws;
    const __hip_bfloat16* whtp = (const __hip_bfloat16*)((const char*)ws + WS_WHT);
    const __hip_bfloat16* wrlp = (const __hip_bfloat16*)((const char*)ws + WS_WRL);
    const __hip_bfloat16* bhtp = (const __hip_bfloat16*)((const char*)ws + WS_BHT);
    const __hip_bfloat16* brlp = (const __hip_bfloat16*)((const char*)ws + WS_BRL);

    const int tid = threadIdx.x;
    const int bt  = blockIdx.x;
    const bool f32      = flags[0] != 0;
    const int idsStride = flags[1] ? 2 : 1;   // int64: read low word

    // ---- issue ids load first ----
    int myid = 0;
    if (tid < NROWS) myid = ids[(bt * NROWS + tid) * idsStride];

    // ---- zero row pads (elems 100-103 of each row) + bytes [31200,31232)
    //      (branchless over-read targets; NaN-bit safety; max over-read 31216+8) ----
    for (int i = tid; i < 154; i += 256) {
        int byteoff = (i < 150) ? (i * (TP * 2) + 200) : (31200 + (i - 150) * 8);
        *(uint2*)(sX + byteoff) = make_uint2(0u, 0u);
    }
    if (tid < NROWS) sIds[tid] = myid;
    __syncthreads();

    // ---- gather 150 rows -> LDS bf16 (on-the-fly cvt for fp32) ----
    if (f32) {
        const float* embf = (const float*)emb_raw;
        gather_f32<8>(embf, sIds, sX, tid, 0);
        gather_f32<7>(embf, sIds, sX, tid, 8);
    } else {
        const __hip_bfloat16* embh = (const __hip_bfloat16*)emb_raw;
        gather_b16raw<8>(embh, sIds, sX, tid, 0);
        gather_b16raw<7>(embh, sIds, sX, tid, 8);
    }
    __syncthreads();
    // After this barrier sIds is dead; sEp/sAl may overwrite [31232,32512).
    // All GEMM/epilogue LDS reads stay < 31232 (max over-read byte 31216+8).

    const int lane = tid & 63;
    const int w    = tid >> 6;
    const int n    = lane & 15;       // B col (feature) / A row-within-tile selector
    const int q    = lane >> 4;       // quad: k-slice q*8 within each 32-k window
    const int nt0  = (w < 3) ? 2 * w : 6;
    const int nt1  = (w < 3) ? 2 * w + 1 : 6;     // wave3 dup of tile 6, masked
    const float m1 = (w < 3) ? 1.f : 0.f;

    const __hip_bfloat16* sxe = (const __hip_bfloat16*)sX;

    // A head-row bases for the 4 m-tiles (clamped; rows >= 50 are discarded)
    int hb[4];
    #pragma unroll
    for (int m = 0; m < 4; m++) {
        int ar = m * 16 + n;
        ar = (ar < KK) ? ar : (KK - 1);
        hb[m] = 3 * ar * TP;
    }

    // ---- head_tail GEMM: K=224 packed [head 112 | tail 112] ----
    f32x4 accH[4][2];
    #pragma unroll
    for (int m = 0; m < 4; m++)
        #pragma unroll
        for (int t = 0; t < 2; t++)
            #pragma unroll
            for (int j = 0; j < 4; j++) accH[m][t][j] = 0.f;

    #pragma unroll
    for (int ks = 0; ks < 7; ks++) {
        const int c    = ks * 4 + q;
        const int aoff = (c < 14) ? (c * 8) : (2 * TP + (c - 14) * 8);
        s8v b0 = *(const s8v*)(whtp + (nt0 * 16 + n) * KHT + ks * 32 + q * 8);
        s8v b1 = *(const s8v*)(whtp + (nt1 * 16 + n) * KHT + ks * 32 + q * 8);
        #pragma unroll
        for (int m = 0; m < 4; m++) {
            s8v a = *(const s8v*)(sxe + hb[m] + aoff);
            accH[m][0] = mfma16x16x32_bf16(a, b0, accH[m][0]);
            accH[m][1] = mfma16x16x32_bf16(a, b1, accH[m][1]);
        }
    }

    const float bh0 = bf2f(bhtp[nt0 * 16 + n]);
    const float bh1 = bf2f(bhtp[nt1 * 16 + n]);
    float htv[4][2][4];
    #pragma unroll
    for (int m = 0; m < 4; m++)
        #pragma unroll
        for (int j = 0; j < 4; j++) {
            htv[m][0][j] = tanh_fast(accH[m][0][j] + bh0);
            htv[m][1][j] = tanh_fast(accH[m][1][j] + bh1);
        }

    // ---- relation GEMM: K=128; rel row at hb+TP; c up to 15 rolls into tail x W0 ----
    f32x4 accR[4][2];
    #pragma unroll
    for (int m = 0; m < 4; m++)
        #pragma unroll
        for (int t = 0; t < 2; t++)
            #pragma unroll
            for (int j = 0; j < 4; j++) accR[m][t][j] = 0.f;

    #pragma unroll
    for (int ks = 0; ks < 4; ks++) {
        const int c    = ks * 4 + q;
        const int aoff = TP + c * 8;
        s8v b0 = *(const s8v*)(wrlp + (nt0 * 16 + n) * KRL + ks * 32 + q * 8);
        s8v b1 = *(const s8v*)(wrlp + (nt1 * 16 + n) * KRL + ks * 32 + q * 8);
        #pragma unroll
        for (int m = 0; m < 4; m++) {
            s8v a = *(const s8v*)(sxe + hb[m] + aoff);
            accR[m][0] = mfma16x16x32_bf16(a, b0, accR[m][0]);
            accR[m][1] = mfma16x16x32_bf16(a, b1, accR[m][1]);
        }
    }

    // ---- combine: dj[m][j] = sum over this wave's d-tiles (t=1 masked for w=3) ----
    const float br0 = bf2f(brlp[nt0 * 16 + n]);
    const float br1 = bf2f(brlp[nt1 * 16 + n]);
    float dj[4][4];
    #pragma unroll
    for (int m = 0; m < 4; m++)
        #pragma unroll
        for (int j = 0; j < 4; j++)
            dj[m][j] = (accR[m][0][j] + br0) * htv[m][0][j]
                     + m1 * (accR[m][1][j] + br1) * htv[m][1][j];

    // reduce over the 16 n-lanes of each quad
    #pragma unroll
    for (int mask = 1; mask < 16; mask <<= 1)
        #pragma unroll
        for (int m = 0; m < 4; m++)
            #pragma unroll
            for (int j = 0; j < 4; j++)
                dj[m][j] += __shfl_xor(dj[m][j], mask, 64);

    if (n == 0) {
        #pragma unroll
        for (int m = 0; m < 4; m++)
            #pragma unroll
            for (int j = 0; j < 4; j++)
                sEp[w * 64 + m * 16 + q * 4 + j] = dj[m][j];   // kt>=50 harmless
    }
    __syncthreads();

    // ---- softmax over KK triples (wave 0 sums the 4 wave-partials) ----
    if (tid < 64) {
        float e = sEp[0 * 64 + tid] + sEp[1 * 64 + tid]
                + sEp[2 * 64 + tid] + sEp[3 * 64 + tid];
        float v = (tid < KK) ? e : -3.0e38f;
        float mx = v;
        #pragma unroll
        for (int mask = 1; mask < 64; mask <<= 1) mx = fmaxf(mx, __shfl_xor(mx, mask, 64));
        float p = (tid < KK) ? __expf(v - mx) : 0.f;
        float s = p;
        #pragma unroll
        for (int mask = 1; mask < 64; mask <<= 1) s += __shfl_xor(s, mask, 64);
        if (tid < KK) sAl[tid] = p / s;
    }
    __syncthreads();

    // ---- output: out[bt][d] = sum_k alpha[k] * head_tail[k][d] (LDS bf16 rows) ----
    if (tid < TWO_D) {
        const int half  = tid / DD;            // 0=head, 1=tail
        const int dmod  = tid - half * DD;
        const int roff  = half ? 2 : 0;
        float acc = 0.f;
        #pragma unroll 10
        for (int k = 0; k < KK; k++)
            acc += sAl[k] * bf2f(sxe[(3 * k + roff) * TP + dmod]);
        out[(size_t)bt * TWO_D + tid] = acc;
    }
}

extern "C" void kernel_launch(void* const* d_in, const int* in_sizes, int n_in,
                              void* d_out, int out_size, void* d_ws, size_t ws_size,
                              hipStream_t stream) {
    const int*  ids = (const int*)d_in[1];
    const void* emb = d_in[3];
    const void* Wht = d_in[4];
    const void* bht = d_in[5];
    const void* Wrl = d_in[6];
    const void* brl = d_in[7];
    float* out = (float*)d_out;

    const int nbt = in_sizes[1] / NROWS;   // B*T blocks

    hipLaunchKernelGGL(prep_weights, dim3(64), dim3(256), 0, stream,
                       Wht, bht, Wrl, brl,
                       (const unsigned int*)emb, (const unsigned int*)ids, d_ws);
    hipLaunchKernelGGL(fused_outer_encoder, dim3(nbt), dim3(256), 0, stream,
                       ids, emb, (const void*)d_ws, out);
}

// Round 14
// 360.682 us; speedup vs baseline: 1.3785x; 1.0297x over previous
//
#include <hip/hip_runtime.h>
#include <hip/hip_bf16.h>

#define KK 50      // triples per (b,t)
#define DD 100
#define TWO_D 200
#define DPAD 112   // padded output-feature dim (7 * 16)
#define KHT 224    // packed K for head_tail gemm: [head 100+pad12 | tail 100+pad12]
#define KRL 128    // padded K for relation gemm (4 * 32)

#define NROWS 150  // 50 triples * {head, rel, tail}
#define TP 104     // LDS row pitch (bf16 elems) = 208 B
#define SX_BYTES 32768          // rows 0..149 data, rest zeroed over-read pad
#define NCH_RAW (NROWS * 25)    // 3750 4-elem chunks per block

// workspace layout (bytes)
#define WS_FLAGS 0                        // [0]=f32 [1]=ids64
#define WS_WHT 256                        // bf16[DPAD*KHT]  = 50176 B
#define WS_WRL (WS_WHT + DPAD*KHT*2)      // bf16[DPAD*KRL]  = 28672 B
#define WS_BHT (WS_WRL + DPAD*KRL*2)      // bf16[DPAD] (256 B slot)
#define WS_BRL (WS_BHT + 256)

typedef __attribute__((ext_vector_type(8))) short        s8v;
typedef __attribute__((ext_vector_type(8))) __bf16       b8v;
typedef __attribute__((ext_vector_type(4))) __bf16       b4v;
typedef __attribute__((ext_vector_type(4))) float        f32x4;

// --- MFMA shim: tolerate either builtin signature (short8 or bf16x8 operands) ---
template <typename T>
__device__ __forceinline__ auto mfma_try(T a, T b, f32x4 c, int)
    -> decltype(__builtin_amdgcn_mfma_f32_16x16x32_bf16(a, b, c, 0, 0, 0)) {
    return __builtin_amdgcn_mfma_f32_16x16x32_bf16(a, b, c, 0, 0, 0);
}
template <typename T, typename U = b8v>
__device__ __forceinline__ f32x4 mfma_try(T a, T b, f32x4 c, long) {
    U ab = __builtin_bit_cast(U, a);
    U bb = __builtin_bit_cast(U, b);
    return __builtin_amdgcn_mfma_f32_16x16x32_bf16(ab, bb, c, 0, 0, 0);
}
__device__ __forceinline__ f32x4 mfma16x16x32_bf16(s8v a, s8v b, f32x4 c) {
    return mfma_try(a, b, c, 0);
}

__device__ __forceinline__ float bf2f(__hip_bfloat16 h) { return __bfloat162float(h); }

__device__ __forceinline__ float tanh_fast(float x) {
    float e = __expf(2.f * x);
    return 1.f - 2.f * __builtin_amdgcn_rcpf(e + 1.f);
}

// ---------- weight prep with SELF-DETECTION (merged detect; verified r12/r13) ------
__global__ void prep_weights(const void* __restrict__ Wht, const void* __restrict__ bht,
                             const void* __restrict__ Wrl, const void* __restrict__ brl,
                             const unsigned int* __restrict__ emb_raw,
                             const unsigned int* __restrict__ ids_raw,
                             void* __restrict__ ws) {
    __shared__ int sFlags[2];
    const int tid = threadIdx.x;
    if (tid < 64) {
        int f32d = 0;
        #pragma unroll
        for (int rep = 0; rep < 4; rep++) {
            unsigned int wd = emb_raw[tid + rep * 64];
            unsigned int e0 = (wd >> 7)  & 0xFF;
            unsigned int e1 = (wd >> 23) & 0xFF;
            if (e0 >= 0x87 || e1 >= 0x87) f32d = 1;   // |x|>=256 impossible
        }
        unsigned long long mf = __ballot(f32d != 0);
        unsigned long long mz = __ballot(ids_raw[2 * tid + 1] == 0u);
        if (tid == 0) {
            sFlags[0] = mf ? 1 : 0;
            sFlags[1] = (__popcll(mz) >= 32) ? 1 : 0;
        }
    }
    __syncthreads();
    const bool f32 = sFlags[0] != 0;
    if (blockIdx.x == 0 && tid == 0) {
        ((int*)ws)[0] = sFlags[0];
        ((int*)ws)[1] = sFlags[1];
    }

    __hip_bfloat16* whtp = (__hip_bfloat16*)((char*)ws + WS_WHT);
    __hip_bfloat16* wrlp = (__hip_bfloat16*)((char*)ws + WS_WRL);
    __hip_bfloat16* bhtp = (__hip_bfloat16*)((char*)ws + WS_BHT);
    __hip_bfloat16* brlp = (__hip_bfloat16*)((char*)ws + WS_BRL);

    const int gid = blockIdx.x * blockDim.x + tid;
    const int gs  = gridDim.x * blockDim.x;

    // ht feature axis packed: k<112 -> head k (k<100 else 0); k>=112 -> tail k-112.
    for (int i = gid; i < DPAD * KHT; i += gs) {
        int d = i / KHT, f = i - d * KHT;
        int src = -1;
        if (f < 112) { if (f < DD) src = f; }
        else { int t = f - 112; if (t < DD) src = DD + t; }
        float v = 0.f;
        if (d < DD && src >= 0)
            v = f32 ? ((const float*)Wht)[d * TWO_D + src]
                    : bf2f(((const __hip_bfloat16*)Wht)[d * TWO_D + src]);
        whtp[i] = __float2bfloat16(v);
    }
    for (int i = gid; i < DPAD * KRL; i += gs) {
        int d = i / KRL, f = i - d * KRL;
        float v = 0.f;
        if (d < DD && f < DD)
            v = f32 ? ((const float*)Wrl)[d * DD + f]
                    : bf2f(((const __hip_bfloat16*)Wrl)[d * DD + f]);
        wrlp[i] = __float2bfloat16(v);
    }
    for (int i = gid; i < DPAD; i += gs) {
        float vh = 0.f, vr = 0.f;
        if (i < DD) {
            vh = f32 ? ((const float*)bht)[i] : bf2f(((const __hip_bfloat16*)bht)[i]);
            vr = f32 ? ((const float*)brl)[i] : bf2f(((const __hip_bfloat16*)brl)[i]);
        }
        bhtp[i] = __float2bfloat16(vh);
        brlp[i] = __float2bfloat16(vr);
    }
}

// ---------- gathers into LINEAR LDS: row seg at byte seg*208 (pitch 104 elems) ------
// 25 4-elem chunks per row; dst byte = seg*208 + off*2. doff<0 = skip (tail lanes).
template <int CNT>
__device__ __forceinline__ void gather_f32(const float* __restrict__ embf,
                                           const int* __restrict__ sIds,
                                           char* __restrict__ sX, int tid, int base) {
    float4 v[CNT];
    int doff[CNT];
    #pragma unroll
    for (int i = 0; i < CNT; ++i) {
        int c = tid + (base + i) * 256;
        bool ok = (c < NCH_RAW);
        int cc = ok ? c : 0;
        int seg = cc / 25;
        int off = (cc - seg * 25) * 4;
        size_t id = (size_t)sIds[seg];
        v[i] = *(const float4*)(embf + id * DD + off);   // 16B aligned (row = 400B)
        doff[i] = ok ? (seg * (TP * 2) + off * 2) : -1;
    }
    #pragma unroll
    for (int i = 0; i < CNT; ++i) {
        if (doff[i] >= 0) {
            b4v pk = { (__bf16)v[i].x, (__bf16)v[i].y, (__bf16)v[i].z, (__bf16)v[i].w };
            *(b4v*)(sX + doff[i]) = pk;                  // 8B aligned
        }
    }
}

template <int CNT>
__device__ __forceinline__ void gather_b16raw(const __hip_bfloat16* __restrict__ embh,
                                              const int* __restrict__ sIds,
                                              char* __restrict__ sX, int tid, int base) {
    uint2 v[CNT];
    int doff[CNT];
    #pragma unroll
    for (int i = 0; i < CNT; ++i) {
        int c = tid + (base + i) * 256;
        bool ok = (c < NCH_RAW);
        int cc = ok ? c : 0;
        int seg = cc / 25;
        int off = (cc - seg * 25) * 4;
        size_t id = (size_t)sIds[seg];
        v[i] = *(const uint2*)(embh + id * DD + off);    // 8B aligned (row = 200B)
        doff[i] = ok ? (seg * (TP * 2) + off * 2) : -1;
    }
    #pragma unroll
    for (int i = 0; i < CNT; ++i) {
        if (doff[i] >= 0) *(uint2*)(sX + doff[i]) = v[i];
    }
}

// m-batched, d-split GEMM (r11 EXACT structure — 147 us measured, no spill):
//   wave w owns d-tiles {2w, 2w+1} (w<3) or {6, dup-masked} (w=3), computed for
//   ALL 4 m-tiles; B fragments reused 4x per load.
// LDS rows (pitch 104): triple t -> head 3t, rel 3t+1, tail 3t+2. Branchless
// over-reads roll into the next row (finite) x W zero-pad columns -> 0.
__global__ __launch_bounds__(256, 4) void fused_outer_encoder(
    const int* __restrict__ ids,              // int32 or int64 (flagged)
    const void* __restrict__ emb_raw,         // fp32 or bf16 (flagged), [V][DD]
    const void* __restrict__ ws,
    float* __restrict__ out)                  // [NBT][TWO_D] fp32
{
    __shared__ char  sX[SX_BYTES];            // 32 KiB linear row store
    __shared__ int   sIds[NROWS];
    __shared__ float sEp[4][64];              // per-wave partial e_weights
    __shared__ float sAl[64];

    const int* flags = (const int*)ws;
    const __hip_bfloat16* whtp = (const __hip_bfloat16*)((const char*)ws + WS_WHT);
    const __hip_bfloat16* wrlp = (const __hip_bfloat16*)((const char*)ws + WS_WRL);
    const __hip_bfloat16* bhtp = (const __hip_bfloat16*)((const char*)ws + WS_BHT);
    const __hip_bfloat16* brlp = (const __hip_bfloat16*)((const char*)ws + WS_BRL);

    const int tid = threadIdx.x;
    const int bt  = blockIdx.x;
    const bool f32      = flags[0] != 0;
    const int idsStride = flags[1] ? 2 : 1;   // int64: read low word

    // ---- issue ids load first ----
    int myid = 0;
    if (tid < NROWS) myid = ids[(bt * NROWS + tid) * idsStride];

    // ---- zero row pads (elems 100-103 of each row) + tail region beyond row 149
    //      (branchless over-read targets; NaN-bit safety) ----
    for (int i = tid; i < 346; i += 256) {
        int byteoff = (i < 150) ? (i * (TP * 2) + 200) : (NROWS * (TP * 2) + (i - 150) * 8);
        *(uint2*)(sX + byteoff) = make_uint2(0u, 0u);
    }
    if (tid < NROWS) sIds[tid] = myid;
    __syncthreads();

    // ---- gather 150 rows -> LDS bf16 (on-the-fly cvt for fp32) ----
    if (f32) {
        const float* embf = (const float*)emb_raw;
        gather_f32<8>(embf, sIds, sX, tid, 0);
        gather_f32<7>(embf, sIds, sX, tid, 8);
    } else {
        const __hip_bfloat16* embh = (const __hip_bfloat16*)emb_raw;
        gather_b16raw<8>(embh, sIds, sX, tid, 0);
        gather_b16raw<7>(embh, sIds, sX, tid, 8);
    }
    __syncthreads();

    const int lane = tid & 63;
    const int w    = tid >> 6;
    const int n    = lane & 15;       // B col (feature) / A row-within-tile selector
    const int q    = lane >> 4;       // quad: k-slice q*8 within each 32-k window
    const int nt0  = (w < 3) ? 2 * w : 6;
    const int nt1  = (w < 3) ? 2 * w + 1 : 6;     // wave3 dup of tile 6, masked below
    const float m1 = (w < 3) ? 1.f : 0.f;

    const __hip_bfloat16* sxe = (const __hip_bfloat16*)sX;

    // A head-row bases for the 4 m-tiles (clamped; rows >= 50 are discarded)
    int hb[4];
    #pragma unroll
    for (int m = 0; m < 4; m++) {
        int ar = m * 16 + n;
        ar = (ar < KK) ? ar : (KK - 1);
        hb[m] = 3 * ar * TP;
    }

    // ---- head_tail GEMM: K=224 packed [head 112 | tail 112] ----
    f32x4 accH[4][2];
    #pragma unroll
    for (int m = 0; m < 4; m++)
        #pragma unroll
        for (int t = 0; t < 2; t++)
            #pragma unroll
            for (int j = 0; j < 4; j++) accH[m][t][j] = 0.f;

    #pragma unroll
    for (int ks = 0; ks < 7; ks++) {
        const int c    = ks * 4 + q;
        const int aoff = (c < 14) ? (c * 8) : (2 * TP + (c - 14) * 8);
        s8v b0 = *(const s8v*)(whtp + (nt0 * 16 + n) * KHT + ks * 32 + q * 8);
        s8v b1 = *(const s8v*)(whtp + (nt1 * 16 + n) * KHT + ks * 32 + q * 8);
        #pragma unroll
        for (int m = 0; m < 4; m++) {
            s8v a = *(const s8v*)(sxe + hb[m] + aoff);
            accH[m][0] = mfma16x16x32_bf16(a, b0, accH[m][0]);
            accH[m][1] = mfma16x16x32_bf16(a, b1, accH[m][1]);
        }
    }

    const float bh0 = bf2f(bhtp[nt0 * 16 + n]);
    const float bh1 = bf2f(bhtp[nt1 * 16 + n]);
    float htv[4][2][4];
    #pragma unroll
    for (int m = 0; m < 4; m++)
        #pragma unroll
        for (int j = 0; j < 4; j++) {
            htv[m][0][j] = tanh_fast(accH[m][0][j] + bh0);
            htv[m][1][j] = tanh_fast(accH[m][1][j] + bh1);
        }

    // ---- relation GEMM: K=128; rel row at hb+TP; c up to 15 rolls into tail x W0 ----
    f32x4 accR[4][2];
    #pragma unroll
    for (int m = 0; m < 4; m++)
        #pragma unroll
        for (int t = 0; t < 2; t++)
            #pragma unroll
            for (int j = 0; j < 4; j++) accR[m][t][j] = 0.f;

    #pragma unroll
    for (int ks = 0; ks < 4; ks++) {
        const int c    = ks * 4 + q;
        const int aoff = TP + c * 8;
        s8v b0 = *(const s8v*)(wrlp + (nt0 * 16 + n) * KRL + ks * 32 + q * 8);
        s8v b1 = *(const s8v*)(wrlp + (nt1 * 16 + n) * KRL + ks * 32 + q * 8);
        #pragma unroll
        for (int m = 0; m < 4; m++) {
            s8v a = *(const s8v*)(sxe + hb[m] + aoff);
            accR[m][0] = mfma16x16x32_bf16(a, b0, accR[m][0]);
            accR[m][1] = mfma16x16x32_bf16(a, b1, accR[m][1]);
        }
    }

    // ---- combine: dj[m][j] = sum over this wave's d-tiles (t=1 masked for w=3) ----
    const float br0 = bf2f(brlp[nt0 * 16 + n]);
    const float br1 = bf2f(brlp[nt1 * 16 + n]);
    float dj[4][4];
    #pragma unroll
    for (int m = 0; m < 4; m++)
        #pragma unroll
        for (int j = 0; j < 4; j++)
            dj[m][j] = (accR[m][0][j] + br0) * htv[m][0][j]
                     + m1 * (accR[m][1][j] + br1) * htv[m][1][j];

    // reduce over the 16 n-lanes of each quad
    #pragma unroll
    for (int mask = 1; mask < 16; mask <<= 1)
        #pragma unroll
        for (int m = 0; m < 4; m++)
            #pragma unroll
            for (int j = 0; j < 4; j++)
                dj[m][j] += __shfl_xor(dj[m][j], mask, 64);

    if (n == 0) {
        #pragma unroll
        for (int m = 0; m < 4; m++)
            #pragma unroll
            for (int j = 0; j < 4; j++)
                sEp[w][m * 16 + q * 4 + j] = dj[m][j];   // kt>=50 slots harmless
    }
    __syncthreads();

    // ---- softmax over KK triples (wave 0 sums the 4 wave-partials) ----
    if (tid < 64) {
        float e = sEp[0][tid] + sEp[1][tid] + sEp[2][tid] + sEp[3][tid];
        float v = (tid < KK) ? e : -3.0e38f;
        float mx = v;
        #pragma unroll
        for (int mask = 1; mask < 64; mask <<= 1) mx = fmaxf(mx, __shfl_xor(mx, mask, 64));
        float p = (tid < KK) ? __expf(v - mx) : 0.f;
        float s = p;
        #pragma unroll
        for (int mask = 1; mask < 64; mask <<= 1) s += __shfl_xor(s, mask, 64);
        if (tid < KK) sAl[tid] = p / s;
    }
    __syncthreads();

    // ---- output: out[bt][d] = sum_k alpha[k] * head_tail[k][d] (LDS bf16 rows) ----
    if (tid < TWO_D) {
        const int half  = tid / DD;            // 0=head, 1=tail
        const int dmod  = tid - half * DD;
        const int roff  = half ? 2 : 0;
        float acc = 0.f;
        #pragma unroll 10
        for (int k = 0; k < KK; k++)
            acc += sAl[k] * bf2f(sxe[(3 * k + roff) * TP + dmod]);
        out[(size_t)bt * TWO_D + tid] = acc;
    }
}

extern "C" void kernel_launch(void* const* d_in, const int* in_sizes, int n_in,
                              void* d_out, int out_size, void* d_ws, size_t ws_size,
                              hipStream_t stream) {
    const int*  ids = (const int*)d_in[1];
    const void* emb = d_in[3];
    const void* Wht = d_in[4];
    const void* bht = d_in[5];
    const void* Wrl = d_in[6];
    const void* brl = d_in[7];
    float* out = (float*)d_out;

    const int nbt = in_sizes[1] / NROWS;   // B*T blocks

    hipLaunchKernelGGL(prep_weights, dim3(64), dim3(256), 0, stream,
                       Wht, bht, Wrl, brl,
                       (const unsigned int*)emb, (const unsigned int*)ids, d_ws);
    hipLaunchKernelGGL(fused_outer_encoder, dim3(nbt), dim3(256), 0, stream,
                       ids, emb, (const void*)d_ws, out);
}